// Round 2
// baseline (1190.574 us; speedup 1.0000x reference)
//
#include <hip/hip_runtime.h>
#include <stdint.h>

// CGIterator on MI355X (gfx950) — fully fused: one wave owns one row n.
// Stream storage: offset = l*l*NK + (n*(2l+1)+loc)*128 + k, NK = N*K.

#define NK (16384 * 128)

typedef float f32x4 __attribute__((ext_vector_type(4)));
typedef short short8 __attribute__((ext_vector_type(8)));
typedef __bf16 bf16x8 __attribute__((ext_vector_type(8)));
typedef uint32_t u32x4 __attribute__((ext_vector_type(4)));

typedef short8 short8a __attribute__((may_alias));
typedef f32x4 f32x4a __attribute__((may_alias));
typedef uint32_t u32a __attribute__((may_alias));
typedef float floata __attribute__((may_alias));

__device__ __forceinline__ uint16_t f2b(float f) {   // f32 -> bf16 bits, RNE
  uint32_t u = __builtin_bit_cast(uint32_t, f);
  u += 0x7FFFu + ((u >> 16) & 1u);
  return (uint16_t)(u >> 16);
}
__device__ __forceinline__ float b2f(uint16_t h) {
  uint32_t u = ((uint32_t)h) << 16;
  return __builtin_bit_cast(float, u);
}
__device__ __forceinline__ uint32_t pk2(float lo, float hi) {  // packed bf16(lo)|bf16(hi)<<16
  uint32_t r;
  asm("v_cvt_pk_bf16_f32 %0, %1, %2" : "=v"(r) : "v"(lo), "v"(hi));
  return r;
}
__device__ __forceinline__ f32x4 mfma_bf16(short8 a, short8 b, f32x4 c) {
  return __builtin_amdgcn_mfma_f32_16x16x32_bf16(
      __builtin_bit_cast(bf16x8, a), __builtin_bit_cast(bf16x8, b), c, 0, 0, 0);
}
__device__ __forceinline__ int l_of_m(int m) { return (m > 0) + (m > 3) + (m > 8); }

// ---------------------------------------------------------------------------
// K0: prep — bf16-transpose weights ([k][q] -> [q][k]) and build Ccat[16][256].
// ---------------------------------------------------------------------------
__global__ __launch_bounds__(256) void k0_prep(
    const float* __restrict__ mixw, const float* __restrict__ iterw,
    const float* __restrict__ cg,
    uint16_t* __restrict__ wtmix, uint16_t* __restrict__ wtiter,
    uint16_t* __restrict__ ccat) {
  int idx = blockIdx.x * 256 + threadIdx.x;
  const int NMIX = 3 * 4 * 16384, NITR = 2 * 4 * 16384;
  if (idx < NMIX) {
    int il = idx >> 14, rem = idx & 16383, q = rem >> 7, k = rem & 127;
    wtmix[idx] = f2b(mixw[il * 16384 + k * 128 + q]);
  } else if (idx < NMIX + NITR) {
    int o = idx - NMIX;
    int tl = o >> 14, rem = o & 16383, q = rem >> 7, k = rem & 127;
    wtiter[o] = f2b(iterw[tl * 16384 + k * 128 + q]);
  } else if (idx < NMIX + NITR + 4096) {
    int o = idx - NMIX - NITR;
    int mg = o >> 8, ij = o & 255, ig = ij >> 4, jg = ij & 15;
    int l = l_of_m(mg), m = mg - l * l;
    int l1 = l_of_m(ig), i = ig - l1 * l1;
    int l2 = l_of_m(jg), j = jg - l2 * l2;
    ccat[o] = f2b(cg[(l1 * 16 + l2 * 4 + l) * 343 + i * 49 + j * 7 + m]);
  }
}

// ---------------------------------------------------------------------------
// Fused: mixing (masked per-l) -> 2x { TP -> masked linear -> add } -> store.
// One wave per row n; 4 waves/block; all LDS wave-private (no barriers).
// Per-wave LDS: c_t [128][20] bf16 (2560 u16) | b_t [128][24] bf16 (3072 u16).
// t_s ([16][128] swizzled) overlays c_t; out_s ([16][132] f32) overlays both.
// ---------------------------------------------------------------------------
__global__ __launch_bounds__(256, 2) void k_fused(
    const float* __restrict__ f0, const float* __restrict__ f1,
    const float* __restrict__ f2, const float* __restrict__ f3,
    const uint16_t* __restrict__ wtmix, const uint16_t* __restrict__ wtiter,
    const uint16_t* __restrict__ ccat, float* __restrict__ out) {
  __shared__ __align__(16) uint16_t lds[4][5632];
  const int lane = threadIdx.x & 63, wid = threadIdx.x >> 6;
  const int g = lane >> 4, r = lane & 15;
  const int n = blockIdx.x * 4 + wid;
  uint16_t* const ct = lds[wid];          // c_t [k][20]; later t_s / out_s
  uint16_t* const bt = ct + 2560;         // b_t [k][24]

  const int lr = l_of_m(r), locr = r - lr * lr;
  const float* Fp = (lr == 0) ? f0 : (lr == 1) ? f1 : (lr == 2) ? f2 : f3;
  Fp += ((size_t)n * (2 * lr + 1) + locr) * 128;

  // ---- feats A-fragments: af[kk][e] = bf16(F[r][kk*32+g*8+e]) ----
  short8 af[4];
#pragma unroll
  for (int kk = 0; kk < 4; ++kk) {
    f32x4 x = *(const f32x4a*)(Fp + kk * 32 + g * 8);
    f32x4 y = *(const f32x4a*)(Fp + kk * 32 + g * 8 + 4);
    u32x4 p = {pk2(x[0], x[1]), pk2(x[2], x[3]), pk2(y[0], y[1]), pk2(y[2], y[3])};
    af[kk] = __builtin_bit_cast(short8, p);
  }

  // masked GEMM over 4 l-blocks: acc[qt] += frags(row-l masked) @ W[lb]
  auto gemm_masked = [&](f32x4 (&acc)[8], const short8 (&fr)[4],
                         const uint16_t* Wb) {
    const short8 z = {0, 0, 0, 0, 0, 0, 0, 0};
    for (int lb = 0; lb < 4; ++lb) {           // rolled: I-cache
      const bool on = (lr == lb);
      short8 s0 = on ? fr[0] : z, s1 = on ? fr[1] : z;
      short8 s2 = on ? fr[2] : z, s3 = on ? fr[3] : z;
      const uint16_t* W = Wb + lb * 16384;     // [q][k] bf16
#pragma unroll
      for (int qt = 0; qt < 8; ++qt) {
        const uint16_t* Wq = W + (qt * 16 + r) * 128 + g * 8;
        acc[qt] = mfma_bf16(s0, *(const short8a*)(Wq), acc[qt]);
        acc[qt] = mfma_bf16(s1, *(const short8a*)(Wq + 32), acc[qt]);
        acc[qt] = mfma_bf16(s2, *(const short8a*)(Wq + 64), acc[qt]);
        acc[qt] = mfma_bf16(s3, *(const short8a*)(Wq + 96), acc[qt]);
      }
    }
  };

  // ---- mixing: cur = mixed0 (f32), m1p/m2p = mixed1/2 (packed bf16) ----
  f32x4 cur[8], tm[8];
  uint32_t m1p[16], m2p[16];
#pragma unroll
  for (int qt = 0; qt < 8; ++qt) cur[qt] = f32x4{0, 0, 0, 0};
  gemm_masked(cur, af, wtmix);
#pragma unroll
  for (int qt = 0; qt < 8; ++qt) tm[qt] = f32x4{0, 0, 0, 0};
  gemm_masked(tm, af, wtmix + 4 * 16384);
#pragma unroll
  for (int qt = 0; qt < 8; ++qt) {
    m1p[qt * 2] = pk2(tm[qt][0], tm[qt][1]);
    m1p[qt * 2 + 1] = pk2(tm[qt][2], tm[qt][3]);
  }
#pragma unroll
  for (int qt = 0; qt < 8; ++qt) tm[qt] = f32x4{0, 0, 0, 0};
  gemm_masked(tm, af, wtmix + 8 * 16384);
#pragma unroll
  for (int qt = 0; qt < 8; ++qt) {
    m2p[qt * 2] = pk2(tm[qt][0], tm[qt][1]);
    m2p[qt * 2 + 1] = pk2(tm[qt][2], tm[qt][3]);
  }

  const int jb = (g & 1) * 8, ih = g >> 1;

  // ---- one CG iteration: TP(cur, mixed) -> masked linear -> += cur ----
  auto iter = [&](const uint32_t (&mp)[16], const uint16_t* Wit) {
    // build c_t[k][20] from cur, b_t[k][24] from mp (k = qt*16+r, m = g*4+j)
#pragma unroll
    for (int qt = 0; qt < 8; ++qt) {
      const int k = qt * 16 + r;
      *(u32a*)&ct[k * 20 + g * 4] = pk2(cur[qt][0], cur[qt][1]);
      *(u32a*)&ct[k * 20 + g * 4 + 2] = pk2(cur[qt][2], cur[qt][3]);
      *(u32a*)&bt[k * 24 + g * 4] = mp[qt * 2];
      *(u32a*)&bt[k * 24 + g * 4 + 2] = mp[qt * 2 + 1];
    }
    // TP: acc[ki] = sum_cc Ccat_frag(cc) @ P_frag(cc,ki), P built in-register.
    f32x4 acc[8];
#pragma unroll
    for (int ki = 0; ki < 8; ++ki) acc[ki] = f32x4{0, 0, 0, 0};
    for (int cc = 0; cc < 8; ++cc) {           // rolled: I-cache
      const short8 cfr = *(const short8a*)(ccat + r * 256 + cc * 32 + g * 8);
#pragma unroll
      for (int ki = 0; ki < 8; ++ki) {
        const int k = ki * 16 + r;
        short8 bw = *(const short8a*)&bt[k * 24 + jb];
        u32x4 bu = __builtin_bit_cast(u32x4, bw);
        const float av = b2f(ct[k * 20 + cc * 2 + ih]);
        float bf0 = __builtin_bit_cast(float, bu[0] << 16);
        float bf1 = __builtin_bit_cast(float, bu[0] & 0xffff0000u);
        float bf2 = __builtin_bit_cast(float, bu[1] << 16);
        float bf3 = __builtin_bit_cast(float, bu[1] & 0xffff0000u);
        float bf4 = __builtin_bit_cast(float, bu[2] << 16);
        float bf5 = __builtin_bit_cast(float, bu[2] & 0xffff0000u);
        float bf6 = __builtin_bit_cast(float, bu[3] << 16);
        float bf7 = __builtin_bit_cast(float, bu[3] & 0xffff0000u);
        u32x4 pu = {pk2(av * bf0, av * bf1), pk2(av * bf2, av * bf3),
                    pk2(av * bf4, av * bf5), pk2(av * bf6, av * bf7)};
        acc[ki] = mfma_bf16(cfr, __builtin_bit_cast(short8, pu), acc[ki]);
      }
    }
    // t_s[m][k] (XOR-swizzled, overlays c_t) <- acc
#pragma unroll
    for (int ki = 0; ki < 8; ++ki) {
      const int k = ki * 16 + r;
#pragma unroll
      for (int j = 0; j < 4; ++j) {
        const int m = g * 4 + j;
        ct[m * 128 + (k ^ ((m & 12) << 2))] = (uint16_t)pk2(acc[ki][j], acc[ki][j]);
      }
    }
    // linear A-fragments from t_s; masked GEMM accumulates into cur.
    short8 afl[4];
#pragma unroll
    for (int kk = 0; kk < 4; ++kk)
      afl[kk] = *(const short8a*)&ct[r * 128 + ((kk * 32 + g * 8) ^ ((r & 12) << 2))];
    gemm_masked(cur, afl, Wit);
  };

  iter(m1p, wtiter);
  iter(m2p, wtiter + 4 * 16384);

  // ---- store: transpose via out_s [16][132] f32 (overlays c_t+b_t) ----
  floata* outs = (floata*)ct;
#pragma unroll
  for (int qt = 0; qt < 8; ++qt)
#pragma unroll
    for (int j = 0; j < 4; ++j)
      outs[(g * 4 + j) * 132 + qt * 16 + r] = cur[qt][j];
  const int mm = lane >> 2, c3 = lane & 3;
  const int lo = l_of_m(mm), locm = mm - lo * lo;
  float* op = out + (size_t)lo * lo * NK + ((size_t)n * (2 * lo + 1) + locm) * 128 + c3 * 4;
  const floata* ip = outs + mm * 132 + c3 * 4;
#pragma unroll
  for (int q = 0; q < 8; ++q)
    *(f32x4a*)(op + q * 16) = *(const f32x4a*)(ip + q * 16);
}

// ---------------------------------------------------------------------------
extern "C" void kernel_launch(void* const* d_in, const int* in_sizes, int n_in,
                              void* d_out, int out_size, void* d_ws, size_t ws_size,
                              hipStream_t stream) {
  const float* f0    = (const float*)d_in[0];
  const float* f1    = (const float*)d_in[1];
  const float* f2    = (const float*)d_in[2];
  const float* f3    = (const float*)d_in[3];
  const float* mixw  = (const float*)d_in[4];
  const float* iterw = (const float*)d_in[5];
  const float* cg    = (const float*)d_in[6];
  float* out = (float*)d_out;

  // ws (uint16): wtmix 196608 | wtiter 131072 | ccat 4096
  uint16_t* wtmix  = (uint16_t*)d_ws;
  uint16_t* wtiter = wtmix + 196608;
  uint16_t* ccat   = wtiter + 131072;

  k0_prep<<<1296, 256, 0, stream>>>(mixw, iterw, cg, wtmix, wtiter, ccat);
  k_fused<<<4096, 256, 0, stream>>>(f0, f1, f2, f3, wtmix, wtiter, ccat, out);
}

// Round 5
// 658.604 us; speedup vs baseline: 1.8077x; 1.8077x over previous
//
#include <hip/hip_runtime.h>
#include <stdint.h>

// CGIterator on MI355X (gfx950) — block-fused v3 "dumb mode": 8-wave block owns
// 8 rows n; linear LDS layouts, no inline asm, no swizzles, barriers everywhere.
// Stream storage: offset = l*l*NK + (n*(2l+1)+loc)*128 + k, NK = N*K.

#define NK (16384 * 128)

typedef float f32x4 __attribute__((ext_vector_type(4)));
typedef short short8 __attribute__((ext_vector_type(8)));
typedef __bf16 bf16x8 __attribute__((ext_vector_type(8)));

typedef short8 short8a __attribute__((may_alias));
typedef f32x4 f32x4a __attribute__((may_alias));
typedef uint32_t u32a __attribute__((may_alias));
typedef float floata __attribute__((may_alias));

__device__ __forceinline__ uint16_t f2b(float f) {   // f32 -> bf16 bits, RNE
  uint32_t u = __builtin_bit_cast(uint32_t, f);
  u += 0x7FFFu + ((u >> 16) & 1u);
  return (uint16_t)(u >> 16);
}
__device__ __forceinline__ float b2f(uint16_t h) {
  uint32_t u = ((uint32_t)h) << 16;
  return __builtin_bit_cast(float, u);
}
__device__ __forceinline__ f32x4 mfma_bf16(short8 a, short8 b, f32x4 c) {
  return __builtin_amdgcn_mfma_f32_16x16x32_bf16(
      __builtin_bit_cast(bf16x8, a), __builtin_bit_cast(bf16x8, b), c, 0, 0, 0);
}
__device__ __forceinline__ int l_of_m(int m) { return (m > 0) + (m > 3) + (m > 8); }
__device__ __forceinline__ int l_of_t(int t) { return (t >= 1) + (t >= 3) + (t >= 6); }

// Tile-row decode. 16-row tiles per l: t0:l0, t1-2:l1, t3-5:l2, t6-9:l3.
// Returns As row index n*16 + m_flat; pad slots clamp to row 0 (real=false).
__device__ __forceinline__ int trow(int t, int ridx, bool& real) {
  const int l = l_of_t(t);
  const int deg = 2 * l + 1;
  const int p0 = (t - (l * (l + 1)) / 2) * 16 + ridx;
  real = p0 < 8 * deg;
  const int p = real ? p0 : 0;
  const int n = p / deg;
  const int mloc = p - n * deg;
  return n * 16 + l * l + mloc;
}

// GEMM, accumulate: acc[t] += A(tile t) @ W_{l(t)}, output col qt*16+r.
__device__ __forceinline__ void gemm_app(const uint16_t* As, const uint16_t* Wb,
                                         int r, int g, int qt, f32x4* acc) {
#pragma unroll
  for (int t = 0; t < 10; ++t) {
    const int lt = l_of_t(t);
    bool dum;
    const int arow = trow(t, r, dum);
    const uint16_t* Ar = As + arow * 128 + g * 8;
    const uint16_t* Wq = Wb + lt * 16384 + (qt * 16 + r) * 128 + g * 8;
    f32x4 c = acc[t];
#pragma unroll
    for (int kk = 0; kk < 4; ++kk)
      c = mfma_bf16(*(const short8a*)(Ar + kk * 32),
                    *(const short8a*)(Wq + kk * 32), c);
    acc[t] = c;
  }
}

// GEMM, fresh accumulate, pack result to bf16 pairs mp[t*2+{0,1}].
__device__ __forceinline__ void gemm_pack(const uint16_t* As, const uint16_t* Wb,
                                          int r, int g, int qt, uint32_t* mp) {
#pragma unroll
  for (int t = 0; t < 10; ++t) {
    const int lt = l_of_t(t);
    bool dum;
    const int arow = trow(t, r, dum);
    const uint16_t* Ar = As + arow * 128 + g * 8;
    const uint16_t* Wq = Wb + lt * 16384 + (qt * 16 + r) * 128 + g * 8;
    f32x4 c = {0.f, 0.f, 0.f, 0.f};
#pragma unroll
    for (int kk = 0; kk < 4; ++kk)
      c = mfma_bf16(*(const short8a*)(Ar + kk * 32),
                    *(const short8a*)(Wq + kk * 32), c);
    mp[t * 2] = (uint32_t)f2b(c[0]) | ((uint32_t)f2b(c[1]) << 16);
    mp[t * 2 + 1] = (uint32_t)f2b(c[2]) | ((uint32_t)f2b(c[3]) << 16);
  }
}

// ---------------------------------------------------------------------------
// K0: prep — bf16-transpose weights ([k][q] -> [q][k]) and build Ccat[16][256].
// ---------------------------------------------------------------------------
__global__ __launch_bounds__(256) void k0_prep(
    const float* __restrict__ mixw, const float* __restrict__ iterw,
    const float* __restrict__ cg,
    uint16_t* __restrict__ wtmix, uint16_t* __restrict__ wtiter,
    uint16_t* __restrict__ ccat) {
  int idx = blockIdx.x * 256 + threadIdx.x;
  const int NMIX = 3 * 4 * 16384, NITR = 2 * 4 * 16384;
  if (idx < NMIX) {
    int il = idx >> 14, rem = idx & 16383, q = rem >> 7, k = rem & 127;
    wtmix[idx] = f2b(mixw[il * 16384 + k * 128 + q]);
  } else if (idx < NMIX + NITR) {
    int o = idx - NMIX;
    int tl = o >> 14, rem = o & 16383, q = rem >> 7, k = rem & 127;
    wtiter[o] = f2b(iterw[tl * 16384 + k * 128 + q]);
  } else if (idx < NMIX + NITR + 4096) {
    int o = idx - NMIX - NITR;
    int mg = o >> 8, ij = o & 255, ig = ij >> 4, jg = ij & 15;
    int l = l_of_m(mg), m = mg - l * l;
    int l1 = l_of_m(ig), i = ig - l1 * l1;
    int l2 = l_of_m(jg), j = jg - l2 * l2;
    ccat[o] = f2b(cg[(l1 * 16 + l2 * 4 + l) * 343 + i * 49 + j * 7 + m]);
  }
}

// ---------------------------------------------------------------------------
// Fused block kernel: 512 threads = 8 waves; wave w owns channel tile qt=w
// (all n) for GEMMs and row n=w (all channels) for the TP.
// LDS 64KB: As = [128 row][128 k] bf16 linear; Bs = [8 n][128 k][16 m] bf16
// linear; final f32 [128][128] staging overlays both.
// ---------------------------------------------------------------------------
__global__ __launch_bounds__(512) void k_fused(
    const float* __restrict__ f0, const float* __restrict__ f1,
    const float* __restrict__ f2, const float* __restrict__ f3,
    const uint16_t* __restrict__ wtmix, const uint16_t* __restrict__ wtiter,
    const uint16_t* __restrict__ ccat, float* __restrict__ out) {
  __shared__ __align__(16) uint16_t smem[32768];   // 64KB
  uint16_t* const As = smem;            // As[row*128 + k]
  uint16_t* const Bs = smem + 16384;    // Bs[n*2048 + k*16 + m]

  const int tid = threadIdx.x;
  const int lane = tid & 63, wid = tid >> 6;
  const int g = lane >> 4, r = lane & 15;
  const int qt = wid;
  const int nblk = blockIdx.x * 8;

  // zero all LDS (coverage insurance: holes read 0.0, never garbage)
  {
    u32a* z = (u32a*)smem;
    for (int i = 0; i < 32; ++i) z[tid + i * 512] = 0;
  }
  __syncthreads();

  // ---- phase 0: stage feats (bf16) into As, scalar ----
  for (int i = 0; i < 32; ++i) {
    const int elem = tid + i * 512;
    const int row = elem >> 7, k = elem & 127;
    const int nn = row >> 4, mf = row & 15;
    const int l = l_of_m(mf), loc = mf - l * l;
    const float* F = (l == 0) ? f0 : (l == 1) ? f1 : (l == 2) ? f2 : f3;
    As[row * 128 + k] =
        f2b(F[((size_t)(nblk + nn) * (2 * l + 1) + loc) * 128 + k]);
  }
  __syncthreads();

  // ---- mixing: cur = feats@W0 (f32), m1p/m2p = feats@W1/W2 (bf16 packed) ----
  f32x4 cur[10];
#pragma unroll
  for (int t = 0; t < 10; ++t) cur[t] = f32x4{0.f, 0.f, 0.f, 0.f};
  uint32_t m1p[20], m2p[20];
  gemm_app(As, wtmix, r, g, qt, cur);
  gemm_pack(As, wtmix + 4 * 16384, r, g, qt, m1p);
  gemm_pack(As, wtmix + 8 * 16384, r, g, qt, m2p);
  __syncthreads();   // feats reads done; As may be overwritten

  const int ih = g >> 1, jb = (g & 1) * 8;

  // ---- one CG iteration ----
  auto do_iter = [&](const uint32_t (&mp)[20], const uint16_t* Wit) {
    // stage cur -> As (bf16), mp -> Bs (skip pad slots)
#pragma unroll
    for (int t = 0; t < 10; ++t)
#pragma unroll
      for (int j = 0; j < 4; ++j) {
        bool cr;
        const int row = trow(t, g * 4 + j, cr);
        if (cr) {
          As[row * 128 + qt * 16 + r] = f2b(cur[t][j]);
          const int cn = row >> 4, cm = row & 15;
          Bs[cn * 2048 + (qt * 16 + r) * 16 + cm] =
              (uint16_t)(mp[t * 2 + (j >> 1)] >> ((j & 1) * 16));
        }
      }
    __syncthreads();

    // TP for n = wid: tacc = Ccat(16x256) @ P(256x128), P built in-register
    f32x4 tacc[8];
#pragma unroll
    for (int ki = 0; ki < 8; ++ki) tacc[ki] = f32x4{0.f, 0.f, 0.f, 0.f};
#pragma unroll
    for (int cc = 0; cc < 8; ++cc) {
      const short8 cfr = *(const short8a*)(ccat + r * 256 + cc * 32 + g * 8);
      const int arow = wid * 16 + cc * 2 + ih;
#pragma unroll
      for (int ki = 0; ki < 8; ++ki) {
        const int k = ki * 16 + r;
        const float av = b2f(As[arow * 128 + k]);
        const short8 bv = *(const short8a*)&Bs[wid * 2048 + k * 16 + jb];
        short8 pv;
#pragma unroll
        for (int e = 0; e < 8; ++e)
          pv[e] = (short)f2b(av * b2f((uint16_t)bv[e]));
        tacc[ki] = mfma_bf16(cfr, pv, tacc[ki]);
      }
    }
    __syncthreads();   // all As/Bs reads complete before tp overwrite

    // tp -> As rows of n = wid (16 m x 128 k, all real)
#pragma unroll
    for (int ki = 0; ki < 8; ++ki)
#pragma unroll
      for (int j = 0; j < 4; ++j)
        As[(wid * 16 + g * 4 + j) * 128 + ki * 16 + r] = f2b(tacc[ki][j]);
    __syncthreads();

    // cur += tp @ iter_w
    gemm_app(As, Wit, r, g, qt, cur);
    __syncthreads();
  };

  do_iter(m1p, wtiter);
  do_iter(m2p, wtiter + 4 * 16384);

  // ---- final: stage f32 in LDS (overlay), coalesced store ----
  floata* fs = (floata*)smem;   // [128 row][128 k] f32 = 64KB
#pragma unroll
  for (int t = 0; t < 10; ++t)
#pragma unroll
    for (int j = 0; j < 4; ++j) {
      bool cr;
      const int row = trow(t, g * 4 + j, cr);
      if (cr) fs[row * 128 + qt * 16 + r] = cur[t][j];
    }
  __syncthreads();
  {
    const int grp = tid >> 5, t32 = tid & 31;
    const int ns = grp >> 1, mh = (grp & 1) * 8;
    for (int m8 = 0; m8 < 8; ++m8) {
      const int m = mh + m8;
      const int l = l_of_m(m), loc = m - l * l;
      float* op = out + (size_t)l * l * NK +
                  ((size_t)(nblk + ns) * (2 * l + 1) + loc) * 128 + t32 * 4;
      *(f32x4a*)op = *(const f32x4a*)(fs + (ns * 16 + m) * 128 + t32 * 4);
    }
  }
}

// ---------------------------------------------------------------------------
extern "C" void kernel_launch(void* const* d_in, const int* in_sizes, int n_in,
                              void* d_out, int out_size, void* d_ws, size_t ws_size,
                              hipStream_t stream) {
  const float* f0    = (const float*)d_in[0];
  const float* f1    = (const float*)d_in[1];
  const float* f2    = (const float*)d_in[2];
  const float* f3    = (const float*)d_in[3];
  const float* mixw  = (const float*)d_in[4];
  const float* iterw = (const float*)d_in[5];
  const float* cg    = (const float*)d_in[6];
  float* out = (float*)d_out;

  // ws (uint16): wtmix 196608 | wtiter 131072 | ccat 4096
  uint16_t* wtmix  = (uint16_t*)d_ws;
  uint16_t* wtiter = wtmix + 196608;
  uint16_t* ccat   = wtiter + 131072;

  k0_prep<<<1296, 256, 0, stream>>>(mixw, iterw, cg, wtmix, wtiter, ccat);
  k_fused<<<2048, 512, 0, stream>>>(f0, f1, f2, f3, wtmix, wtiter, ccat, out);
}